// Round 2
// baseline (1218.964 us; speedup 1.0000x reference)
//
#include <hip/hip_runtime.h>

// Problem constants: B=32, T=128, NQ=1000, NC=64, DK=128, DA=128
#define B_  32
#define T_  128
#define HS  132   // h_f32 LDS row stride (floats)
#define HBS 136   // h_bf16 LDS row stride (ushorts), 16B-aligned rows

typedef __attribute__((ext_vector_type(8))) short bf16x8;
typedef __attribute__((ext_vector_type(4))) float f32x4;

__device__ __forceinline__ float sigf(float x){ return __builtin_amdgcn_rcpf(1.f + __expf(-x)); }
__device__ __forceinline__ float tanh_f(float x){ return 2.f*__builtin_amdgcn_rcpf(1.f + __expf(-2.f*x)) - 1.f; }
__device__ __forceinline__ unsigned short f2b(float x){
  union { float f; unsigned int u; } v; v.f = x;
  return (unsigned short)((v.u + 0x7FFFu + ((v.u >> 16) & 1u)) >> 16);  // RNE bf16
}
// LDS-only barrier: skips the vmcnt(0) drain __syncthreads() would emit.
// All global loads in the loop are consumed by their issuing thread (compiler
// inserts vmcnt waits at use); H/HT stores are read by nobody in-kernel.
__device__ __forceinline__ void bar_lds(){
  __builtin_amdgcn_sched_barrier(0);
  asm volatile("s_waitcnt lgkmcnt(0)" ::: "memory");
  __builtin_amdgcn_s_barrier();
  __builtin_amdgcn_sched_barrier(0);
}

// ---------------- stage: bf16 weight copies + a-part rowsum of W1 ----------------
__global__ __launch_bounds__(256) void stage_k(
    const float* __restrict__ W2, const float* __restrict__ W3,
    const float* __restrict__ W4, const float* __restrict__ W1,
    unsigned short* __restrict__ W2b, unsigned short* __restrict__ W3b,
    unsigned short* __restrict__ W4b, float* __restrict__ S)
{
  int i = blockIdx.x*256 + threadIdx.x;
  if (i < 128*384){ W2b[i] = f2b(W2[i]); W3b[i] = f2b(W3[i]); }
  if (i < 128*256){ W4b[i] = f2b(W4[i]); }
  if (i < 128){
    float s = 0.f;
    const float* row = W1 + (size_t)i*256 + 128;
    for (int k = 0; k < 128; ++k) s += row[k];
    S[i] = s;   // sum_k W1[i][128+k]  (a_rep constant along DA)
  }
}

// ---------------- prep: q_emb gather, qa GEMM (fp32 exact), pred[:,0]=0 ----------
__global__ __launch_bounds__(256) void prep_k(
    const int* __restrict__ qd, const float* __restrict__ ad,
    const float* __restrict__ qew, const float* __restrict__ W1,
    const float* __restrict__ b1, const float* __restrict__ S,
    float* __restrict__ oqe, float* __restrict__ oqa, float* __restrict__ pred)
{
  __shared__ float qe[16][128];
  __shared__ float w1c[128][65];
  const int tid = threadIdx.x;
  const int bt0 = blockIdx.x * 16;

  for (int i = tid; i < 16*128; i += 256){
    int r = i >> 7, d = i & 127;
    float v = qew[(size_t)qd[bt0 + r]*128 + d];
    qe[r][d] = v;
    oqe[(size_t)(bt0 + r)*128 + d] = v;
  }
  const int j = tid & 127, rh = tid >> 7;
  float accv[8];
  {
    float base = b1[j], Sj = S[j];
#pragma unroll
    for (int r = 0; r < 8; ++r) accv[r] = fmaf(ad[bt0 + rh*8 + r], Sj, base);
  }
  for (int c = 0; c < 2; ++c){
    __syncthreads();
    for (int i = tid; i < 128*64; i += 256){
      int jj = i >> 6, kk = i & 63;
      w1c[jj][kk] = W1[(size_t)jj*256 + c*64 + kk];
    }
    __syncthreads();
#pragma unroll 4
    for (int k = 0; k < 64; ++k){
      float wv = w1c[j][k];
#pragma unroll
      for (int r = 0; r < 8; ++r) accv[r] = fmaf(qe[rh*8 + r][c*64 + k], wv, accv[r]);
    }
  }
#pragma unroll
  for (int r = 0; r < 8; ++r) oqa[(size_t)(bt0 + rh*8 + r)*128 + j] = accv[r];
  if (blockIdx.x == 0 && tid < 32) pred[tid * T_] = 0.f;
}

// ---------------- recur: 127-step recurrence, one block per batch -----------------
struct __align__(16) Sm {
  float hf[64*HS];            // h state fp32
  float qe[3][64];            // qm rows, triple-buffered
  float kcf[128];
  float htp[4*128];           // h_tilde partials per M-tile
  unsigned short hb[64*HBS];  // h state bf16 (MFMA A operand)
  unsigned short cat3[384];   // [learning_pre | learning | h_tilde_pre] bf16
  unsigned short kcb[128];    // KC bf16
  int qdl[T_];                // this batch's qd row
};

__global__ __launch_bounds__(512, 2) void recur_k(
    const int* __restrict__ qd, const float* __restrict__ qmx,
    const float* __restrict__ h0,
    const float* __restrict__ b2, const float* __restrict__ b3,
    const float* __restrict__ b4,
    const unsigned short* __restrict__ W2b, const unsigned short* __restrict__ W3b,
    const unsigned short* __restrict__ W4b,
    const float* __restrict__ oqa,
    float* __restrict__ H, unsigned short* __restrict__ HTg)
{
  __shared__ Sm s;
  const int b   = blockIdx.x;
  const int tid = threadIdx.x;
  const int w = tid >> 6, lane = tid & 63, g = lane >> 4, li = lane & 15;
  const int mt = w & 3, nh = w >> 2;

  // ---- resident weight fragments: W2/W3 rows (w*16+li), all 12 K-chunks
  bf16x8 w2f[12], w3f[12];
#pragma unroll
  for (int ks = 0; ks < 12; ++ks){
    w2f[ks] = *(const bf16x8*)(W2b + (size_t)(w*16 + li)*384 + ks*32 + 8*g);
    w3f[ks] = *(const bf16x8*)(W3b + (size_t)(w*16 + li)*384 + ks*32 + 8*g);
  }
  const float b2v = b2[w*16 + li], b3v = b3[w*16 + li];
  float b4v[4];
#pragma unroll
  for (int r = 0; r < 4; ++r) b4v[r] = b4[(nh*4 + r)*16 + li];

  // ---- init
  for (int i = tid; i < 64*128; i += 512){
    int n = i >> 7, d = i & 127;
    float v = h0[i];
    s.hf[n*HS + d] = v;
    s.hb[n*HBS + d] = f2b(v);
    H[(size_t)b*8192 + i] = sigf(v);
  }
  if (tid < T_) s.qdl[tid] = qd[b*T_ + tid];
  __syncthreads();
  if (tid < 64){
    s.qe[0][tid] = qmx[(size_t)s.qdl[0]*64 + tid];
    s.qe[1][tid] = qmx[(size_t)s.qdl[1]*64 + tid];
  }
  __syncthreads();
  if (tid < 128){   // h_tilde0 + initial cat3
    float acc = 0.f;
    for (int n = 0; n < 64; ++n) acc = fmaf(s.qe[0][n], s.hf[n*HS + tid], acc);
    s.cat3[tid]       = 0;
    s.cat3[128 + tid] = f2b(oqa[(size_t)b*T_*128 + tid]);
    s.cat3[256 + tid] = f2b(acc);
  }
  __syncthreads();

#pragma unroll 1
  for (int t = 0; t < T_-1; ++t){
    // prefetches, consumed in phase D (latency fully hidden)
    float qav = 0.f, qmxv = 0.f;
    if (tid < 128) qav = oqa[((size_t)b*T_ + t+1)*128 + tid];
    if (tid >= 256 && tid < 320 && t+2 < T_)
      qmxv = qmx[(size_t)s.qdl[t+2]*64 + (tid-256)];

    // ---- A: KP/R GEMVs from register weights; fold KC
    {
      bf16x8 av[12];
#pragma unroll
      for (int ks = 0; ks < 12; ++ks) av[ks] = *(const bf16x8*)&s.cat3[ks*32 + 8*g];
      f32x4 a2e = {0,0,0,0}, a2o = {0,0,0,0}, a3e = {0,0,0,0}, a3o = {0,0,0,0};
#pragma unroll
      for (int ks = 0; ks < 12; ks += 2){
        a2e = __builtin_amdgcn_mfma_f32_16x16x32_bf16(av[ks],   w2f[ks],   a2e, 0,0,0);
        a3e = __builtin_amdgcn_mfma_f32_16x16x32_bf16(av[ks],   w3f[ks],   a3e, 0,0,0);
        a2o = __builtin_amdgcn_mfma_f32_16x16x32_bf16(av[ks+1], w2f[ks+1], a2o, 0,0,0);
        a3o = __builtin_amdgcn_mfma_f32_16x16x32_bf16(av[ks+1], w3f[ks+1], a3o, 0,0,0);
      }
      if (g == 0){
        int jj = w*16 + li;
        float kp = tanh_f(a2e[0] + a2o[0] + b2v);
        float rr = sigf (a3e[0] + a3o[0] + b3v);
        float kc = rr*(kp + 1.f)*0.5f;
        s.kcf[jj] = kc; s.kcb[jj] = f2b(kc);
      }
    }
    bar_lds();                             // B1

    // ---- C: fragment loads (reads of h must precede writes)
    bf16x8 af[8];
#pragma unroll
    for (int ks = 0; ks < 4; ++ks) af[ks]   = *(const bf16x8*)&s.hb[(mt*16 + li)*HBS + ks*32 + 8*g];
#pragma unroll
    for (int ks = 0; ks < 4; ++ks) af[4+ks] = *(const bf16x8*)&s.kcb[ks*32 + 8*g];
    float qc[4], qn[4];
#pragma unroll
    for (int r = 0; r < 4; ++r){
      int n = mt*16 + g*4 + r;
      qc[r] = s.qe[t%3][n];
      qn[r] = s.qe[(t+1)%3][n];
    }
    bar_lds();                             // B3

    // ---- C': z = [h|KC]@W4^T ; h = qe*KC + sig(z)*h ; H[t+1] ; ht partials
#pragma unroll
    for (int nt4 = 0; nt4 < 4; ++nt4){
      int nt = nh*4 + nt4;
      int j  = nt*16 + li;
      f32x4 acc = {0,0,0,0};
      const unsigned short* wr = W4b + (size_t)j*256;
#pragma unroll
      for (int ks = 0; ks < 8; ++ks){
        bf16x8 bb = *(const bf16x8*)(wr + ks*32 + 8*g);
        acc = __builtin_amdgcn_mfma_f32_16x16x32_bf16(af[ks], bb, acc, 0, 0, 0);
      }
      float kcj = s.kcf[j];
      float part = 0.f;
#pragma unroll
      for (int r = 0; r < 4; ++r){
        int n = mt*16 + g*4 + r;            // C/D: row=(lane>>4)*4+r, col=lane&15
        float sg = sigf(acc[r] + b4v[nt4]);
        float hp = s.hf[n*HS + j];
        float hn = fmaf(qc[r], kcj, sg*hp);
        s.hf[n*HS + j] = hn;
        s.hb[n*HBS + j] = f2b(hn);
        if (t < T_-2) H[((size_t)(t+1)*B_ + b)*8192 + n*128 + j] = sigf(hn);
        part = fmaf(qn[r], hn, part);
      }
      part += __shfl_xor(part, 16);
      part += __shfl_xor(part, 32);
      if (g == 0) s.htp[mt*128 + j] = part;
    }
    bar_lds();                             // B4

    // ---- D: ht reduce + cat3 shift + HT stash + qe slot write
    if (tid < 128){
      float ht = s.htp[tid] + s.htp[128+tid] + s.htp[256+tid] + s.htp[384+tid];
      unsigned short cur = s.cat3[128 + tid];
      s.cat3[tid]       = cur;
      s.cat3[128 + tid] = f2b(qav);
      s.cat3[256 + tid] = f2b(ht);
      HTg[((size_t)b*T_ + t + 1)*128 + tid] = f2b(ht);
    } else if (tid >= 256 && tid < 320){
      if (t+2 < T_) s.qe[(t+2)%3][tid-256] = qmxv;
    }
    bar_lds();                             // B5
  }
}

// ---------------- ypost: deferred y GEMV over all (b, tau>=1) --------------------
__global__ __launch_bounds__(256) void ypost_k(
    const float* __restrict__ oqe, const unsigned short* __restrict__ HT,
    const float* __restrict__ W5, const float* __restrict__ b5,
    float* __restrict__ pred)
{
  __shared__ float X[32][256];
  __shared__ float w5c[128][33];
  const int tau = blockIdx.x + 1;
  const int tid = threadIdx.x;

  for (int i = tid; i < 32*128; i += 256){
    int bb = i >> 7, k = i & 127;
    X[bb][k] = oqe[((size_t)bb*T_ + tau)*128 + k];
    union { unsigned int u; float f; } cv;
    cv.u = ((unsigned int)HT[((size_t)bb*T_ + tau)*128 + k]) << 16;
    X[bb][128 + k] = cv.f;
  }
  const int j = tid & 127, rh = tid >> 7;
  float acc[16];
  float base = b5[j];
#pragma unroll
  for (int r = 0; r < 16; ++r) acc[r] = base;
  for (int c = 0; c < 8; ++c){
    __syncthreads();
    for (int i = tid; i < 128*32; i += 256){
      int jj = i >> 5, kk = i & 31;
      w5c[jj][kk] = W5[(size_t)jj*256 + c*32 + kk];
    }
    __syncthreads();
#pragma unroll 8
    for (int k = 0; k < 32; ++k){
      float wv = w5c[j][k];
#pragma unroll
      for (int r = 0; r < 16; ++r) acc[r] = fmaf(X[rh*16 + r][c*32 + k], wv, acc[r]);
    }
  }
  __syncthreads();
#pragma unroll
  for (int r = 0; r < 16; ++r) X[rh*16 + r][j] = sigf(acc[r]);
  __syncthreads();
  if (tid < 32){
    float ssum = 0.f;
    for (int k = 0; k < 128; ++k) ssum += X[tid][k];
    pred[tid*T_ + tau] = ssum * (1.f/128.f);
  }
}

extern "C" void kernel_launch(void* const* d_in, const int* in_sizes, int n_in,
                              void* d_out, int out_size, void* d_ws, size_t ws_size,
                              hipStream_t stream)
{
  const int*   qd  = (const int*)  d_in[0];
  const float* ad  = (const float*)d_in[1];
  const float* qmx = (const float*)d_in[2];
  const float* qew = (const float*)d_in[3];
  const float* W1  = (const float*)d_in[4];
  const float* b1  = (const float*)d_in[5];
  const float* W2  = (const float*)d_in[6];
  const float* b2  = (const float*)d_in[7];
  const float* W3  = (const float*)d_in[8];
  const float* b3  = (const float*)d_in[9];
  const float* W4  = (const float*)d_in[10];
  const float* b4  = (const float*)d_in[11];
  const float* W5  = (const float*)d_in[12];
  const float* b5  = (const float*)d_in[13];
  const float* h0  = (const float*)d_in[14];

  float* H    = (float*)d_out;                         // [127][32][64][128]
  float* pred = H    + (size_t)127*32*64*128;          // [32][128]
  float* oqe  = pred + (size_t)32*128;                 // [32][128][128]
  float* oqa  = oqe  + (size_t)32*128*128;             // [32][128][128]

  unsigned short* W2b = (unsigned short*)d_ws;         // [128][384] bf16
  unsigned short* W3b = W2b + 128*384;
  unsigned short* W4b = W3b + 128*384;                 // [128][256] bf16
  float*          S   = (float*)(W4b + 128*256);       // [128]
  unsigned short* HTg = (unsigned short*)(S + 128);    // [32][128][128] bf16 h_tilde

  stage_k<<<192, 256, 0, stream>>>(W2, W3, W4, W1, W2b, W3b, W4b, S);
  prep_k <<<256, 256, 0, stream>>>(qd, ad, qew, W1, b1, S, oqe, oqa, pred);
  recur_k<<<32,  512, 0, stream>>>(qd, qmx, h0, b2, b3, b4,
                                   W2b, W3b, W4b, oqa, H, HTg);
  ypost_k<<<127, 256, 0, stream>>>(oqe, HTg, W5, b5, pred);
}

// Round 3
// 747.082 us; speedup vs baseline: 1.6316x; 1.6316x over previous
//
#include <hip/hip_runtime.h>

// Problem constants: B=32, T=128, NQ=1000, NC=64, DK=128, DA=128
#define B_  32
#define T_  128
#define HFS 132   // h fp32 staging row stride (floats); rows 528B (16B-aligned)
#define HBS 136   // h bf16 LDS row stride (ushorts); rows 272B (16B-aligned)

typedef __attribute__((ext_vector_type(8))) short bf16x8;
typedef __attribute__((ext_vector_type(4))) float f32x4;

__device__ __forceinline__ float sigf(float x){ return __builtin_amdgcn_rcpf(1.f + __expf(-x)); }
__device__ __forceinline__ float tanh_f(float x){ return 2.f*__builtin_amdgcn_rcpf(1.f + __expf(-2.f*x)) - 1.f; }
__device__ __forceinline__ unsigned short f2b(float x){
  union { float f; unsigned int u; } v; v.f = x;
  return (unsigned short)((v.u + 0x7FFFu + ((v.u >> 16) & 1u)) >> 16);  // RNE bf16
}
// LDS-only barrier: skip the vmcnt(0) drain __syncthreads() emits.
__device__ __forceinline__ void bar_lds(){
  __builtin_amdgcn_sched_barrier(0);
  asm volatile("s_waitcnt lgkmcnt(0)" ::: "memory");
  __builtin_amdgcn_s_barrier();
  __builtin_amdgcn_sched_barrier(0);
}

// ---------------- stage: bf16 weight copies + a-part rowsum of W1 ----------------
__global__ __launch_bounds__(256) void stage_k(
    const float* __restrict__ W2, const float* __restrict__ W3,
    const float* __restrict__ W4, const float* __restrict__ W1,
    unsigned short* __restrict__ W2b, unsigned short* __restrict__ W3b,
    unsigned short* __restrict__ W4b, float* __restrict__ S)
{
  int i = blockIdx.x*256 + threadIdx.x;
  if (i < 128*384){ W2b[i] = f2b(W2[i]); W3b[i] = f2b(W3[i]); }
  if (i < 128*256){ W4b[i] = f2b(W4[i]); }
  if (i < 128){
    float s = 0.f;
    const float* row = W1 + (size_t)i*256 + 128;
    for (int k = 0; k < 128; ++k) s += row[k];
    S[i] = s;   // sum_k W1[i][128+k]  (a_rep constant along DA)
  }
}

// ---------------- prep: q_emb gather, qa GEMM (fp32 exact), pred[:,0]=0 ----------
__global__ __launch_bounds__(256) void prep_k(
    const int* __restrict__ qd, const float* __restrict__ ad,
    const float* __restrict__ qew, const float* __restrict__ W1,
    const float* __restrict__ b1, const float* __restrict__ S,
    float* __restrict__ oqe, float* __restrict__ oqa, float* __restrict__ pred)
{
  __shared__ float qe[16][128];
  __shared__ float w1c[128][65];
  const int tid = threadIdx.x;
  const int bt0 = blockIdx.x * 16;

  for (int i = tid; i < 16*128; i += 256){
    int r = i >> 7, d = i & 127;
    float v = qew[(size_t)qd[bt0 + r]*128 + d];
    qe[r][d] = v;
    oqe[(size_t)(bt0 + r)*128 + d] = v;
  }
  const int j = tid & 127, rh = tid >> 7;
  float accv[8];
  {
    float base = b1[j], Sj = S[j];
#pragma unroll
    for (int r = 0; r < 8; ++r) accv[r] = fmaf(ad[bt0 + rh*8 + r], Sj, base);
  }
  for (int c = 0; c < 2; ++c){
    __syncthreads();
    for (int i = tid; i < 128*64; i += 256){
      int jj = i >> 6, kk = i & 63;
      w1c[jj][kk] = W1[(size_t)jj*256 + c*64 + kk];
    }
    __syncthreads();
#pragma unroll 4
    for (int k = 0; k < 64; ++k){
      float wv = w1c[j][k];
#pragma unroll
      for (int r = 0; r < 8; ++r) accv[r] = fmaf(qe[rh*8 + r][c*64 + k], wv, accv[r]);
    }
  }
#pragma unroll
  for (int r = 0; r < 8; ++r) oqa[(size_t)(bt0 + rh*8 + r)*128 + j] = accv[r];
  if (blockIdx.x == 0 && tid < 32) pred[tid * T_] = 0.f;
}

// ---------------- recur: 127-step recurrence, one block per batch -----------------
// Wave map (GEMM): mg = w&1 (M-group of 32 rows), nq = w>>1 (N-group of 32 cols).
// Thread owns h(n,j) for n=(mg*2+mi)*16+g*4+r, j=(nq*2+ni)*16+li -> fp32 h in REGISTERS.
struct __align__(16) Sm {
  float hfs[64*HFS];            // fp32 h staging for coalesced H writes (33.8 KB)
  unsigned short hb[2][64*HBS]; // bf16 h, double-buffered (MFMA A operand) (34.8 KB)
  float qe[3][64];              // qm rows, triple-buffered
  float kcf[128];
  float htp[2*128];             // h_tilde partials per M-group
  unsigned short kcb[128];
  unsigned short cat3[384];     // [learning_pre | learning | h_tilde_pre] bf16
  int qdl[T_];
};

__global__ __launch_bounds__(512) void recur_k(
    const int* __restrict__ qd, const float* __restrict__ qmx,
    const float* __restrict__ h0,
    const float* __restrict__ b2, const float* __restrict__ b3,
    const float* __restrict__ b4,
    const unsigned short* __restrict__ W2b, const unsigned short* __restrict__ W3b,
    const unsigned short* __restrict__ W4b,
    const float* __restrict__ oqa,
    float* __restrict__ H, unsigned short* __restrict__ HTg)
{
  __shared__ Sm s;
  const int b   = blockIdx.x;
  const int tid = threadIdx.x;
  const int w = tid >> 6, lane = tid & 63, g = lane >> 4, li = lane & 15;
  const int mg = w & 1, nq = w >> 1;

  // ---- register-resident weights
  bf16x8 w2f[12], w3f[12];                 // GEMV rows j = w*16+li
#pragma unroll
  for (int ks = 0; ks < 12; ++ks){
    w2f[ks] = *(const bf16x8*)(W2b + (size_t)(w*16 + li)*384 + ks*32 + 8*g);
    w3f[ks] = *(const bf16x8*)(W3b + (size_t)(w*16 + li)*384 + ks*32 + 8*g);
  }
  bf16x8 w4f[2][8];                        // GEMM B rows j = (nq*2+ni)*16+li
#pragma unroll
  for (int ni = 0; ni < 2; ++ni)
#pragma unroll
    for (int ks = 0; ks < 8; ++ks)
      w4f[ni][ks] = *(const bf16x8*)(W4b + (size_t)((nq*2+ni)*16 + li)*256 + ks*32 + 8*g);

  const float b2v = b2[w*16 + li], b3v = b3[w*16 + li];
  float b4v[2];
#pragma unroll
  for (int ni = 0; ni < 2; ++ni) b4v[ni] = b4[(nq*2+ni)*16 + li];

  // ---- fp32 h state in registers
  float hreg[2][2][4];
#pragma unroll
  for (int mi = 0; mi < 2; ++mi)
#pragma unroll
    for (int ni = 0; ni < 2; ++ni)
#pragma unroll
      for (int r = 0; r < 4; ++r){
        int n = (mg*2 + mi)*16 + g*4 + r, j = (nq*2 + ni)*16 + li;
        hreg[mi][ni][r] = h0[n*128 + j];
      }

  // ---- init: hb[0]; H[0] = sigmoid(h0); qd row; qe rows 0,1
  for (int i = tid; i < 64*128; i += 512){
    int n = i >> 7, d = i & 127;
    float v = h0[i];
    s.hb[0][n*HBS + d] = f2b(v);
    H[(size_t)b*8192 + i] = sigf(v);
  }
  if (tid < T_) s.qdl[tid] = qd[b*T_ + tid];
  __syncthreads();
  if (tid < 64){
    s.qe[0][tid] = qmx[(size_t)s.qdl[0]*64 + tid];
    s.qe[1][tid] = qmx[(size_t)s.qdl[1]*64 + tid];
  }
  __syncthreads();
  if (tid < 128){   // h_tilde0 + initial cat3 (learning_pre=0, learning=qa[:,0])
    float acc = 0.f;
    for (int n = 0; n < 64; ++n) acc = fmaf(s.qe[0][n], h0[n*128 + tid], acc);
    s.cat3[tid]       = 0;
    s.cat3[128 + tid] = f2b(oqa[(size_t)b*T_*128 + tid]);
    s.cat3[256 + tid] = f2b(acc);
  }
  __syncthreads();

#pragma unroll 1
  for (int t = 0; t < T_-1; ++t){
    const int cur = t & 1, nxt = cur ^ 1;
    // prefetches (consumed in phase D)
    float qav = 0.f, qmxv = 0.f;
    if (tid < 128) qav = oqa[((size_t)b*T_ + t+1)*128 + tid];
    if (tid >= 256 && tid < 320 && t+2 < T_)
      qmxv = qmx[(size_t)s.qdl[t+2]*64 + (tid-256)];

    // ---- A: KP/R GEMVs from register weights; fold KC
    {
      bf16x8 av[12];
#pragma unroll
      for (int ks = 0; ks < 12; ++ks) av[ks] = *(const bf16x8*)&s.cat3[ks*32 + 8*g];
      f32x4 a2[3] = {{0,0,0,0},{0,0,0,0},{0,0,0,0}};
      f32x4 a3[3] = {{0,0,0,0},{0,0,0,0},{0,0,0,0}};
#pragma unroll
      for (int ks = 0; ks < 4; ++ks){
        a2[0] = __builtin_amdgcn_mfma_f32_16x16x32_bf16(av[ks],   w2f[ks],   a2[0], 0,0,0);
        a3[0] = __builtin_amdgcn_mfma_f32_16x16x32_bf16(av[ks],   w3f[ks],   a3[0], 0,0,0);
        a2[1] = __builtin_amdgcn_mfma_f32_16x16x32_bf16(av[ks+4], w2f[ks+4], a2[1], 0,0,0);
        a3[1] = __builtin_amdgcn_mfma_f32_16x16x32_bf16(av[ks+4], w3f[ks+4], a3[1], 0,0,0);
        a2[2] = __builtin_amdgcn_mfma_f32_16x16x32_bf16(av[ks+8], w2f[ks+8], a2[2], 0,0,0);
        a3[2] = __builtin_amdgcn_mfma_f32_16x16x32_bf16(av[ks+8], w3f[ks+8], a3[2], 0,0,0);
      }
      if (g == 0){
        int jj = w*16 + li;
        float kp = tanh_f(a2[0][0] + a2[1][0] + a2[2][0] + b2v);
        float rr = sigf (a3[0][0] + a3[1][0] + a3[2][0] + b3v);
        float kc = rr*(kp + 1.f)*0.5f;
        s.kcf[jj] = kc; s.kcb[jj] = f2b(kc);
      }
    }
    bar_lds();                             // B1: kcb/kcf ready

    // ---- C': z = [h|KC]@W4^T ; h = qe*KC + sig(z)*h ; staging writes ; ht partials
    {
      bf16x8 af[2][4], kf[4];
#pragma unroll
      for (int mi = 0; mi < 2; ++mi)
#pragma unroll
        for (int ks = 0; ks < 4; ++ks)
          af[mi][ks] = *(const bf16x8*)&s.hb[cur][((mg*2+mi)*16 + li)*HBS + ks*32 + 8*g];
#pragma unroll
      for (int ks = 0; ks < 4; ++ks) kf[ks] = *(const bf16x8*)&s.kcb[ks*32 + 8*g];
      float qc[2][4], qn[2][4];
#pragma unroll
      for (int mi = 0; mi < 2; ++mi)
#pragma unroll
        for (int r = 0; r < 4; ++r){
          int n = (mg*2 + mi)*16 + g*4 + r;
          qc[mi][r] = s.qe[t%3][n];
          qn[mi][r] = s.qe[(t+1)%3][n];
        }
      f32x4 acc[2][2] = {{{0,0,0,0},{0,0,0,0}},{{0,0,0,0},{0,0,0,0}}};
#pragma unroll
      for (int ks = 0; ks < 4; ++ks){
        acc[0][0] = __builtin_amdgcn_mfma_f32_16x16x32_bf16(af[0][ks], w4f[0][ks], acc[0][0], 0,0,0);
        acc[0][1] = __builtin_amdgcn_mfma_f32_16x16x32_bf16(af[0][ks], w4f[1][ks], acc[0][1], 0,0,0);
        acc[1][0] = __builtin_amdgcn_mfma_f32_16x16x32_bf16(af[1][ks], w4f[0][ks], acc[1][0], 0,0,0);
        acc[1][1] = __builtin_amdgcn_mfma_f32_16x16x32_bf16(af[1][ks], w4f[1][ks], acc[1][1], 0,0,0);
      }
#pragma unroll
      for (int ks = 0; ks < 4; ++ks){
        acc[0][0] = __builtin_amdgcn_mfma_f32_16x16x32_bf16(kf[ks], w4f[0][ks+4], acc[0][0], 0,0,0);
        acc[0][1] = __builtin_amdgcn_mfma_f32_16x16x32_bf16(kf[ks], w4f[1][ks+4], acc[0][1], 0,0,0);
        acc[1][0] = __builtin_amdgcn_mfma_f32_16x16x32_bf16(kf[ks], w4f[0][ks+4], acc[1][0], 0,0,0);
        acc[1][1] = __builtin_amdgcn_mfma_f32_16x16x32_bf16(kf[ks], w4f[1][ks+4], acc[1][1], 0,0,0);
      }
      float kcj[2];
#pragma unroll
      for (int ni = 0; ni < 2; ++ni) kcj[ni] = s.kcf[(nq*2+ni)*16 + li];
#pragma unroll
      for (int ni = 0; ni < 2; ++ni){
        int j = (nq*2 + ni)*16 + li;
        float part = 0.f;
#pragma unroll
        for (int mi = 0; mi < 2; ++mi){
#pragma unroll
          for (int r = 0; r < 4; ++r){
            int n = (mg*2 + mi)*16 + g*4 + r;   // C/D: row=(lane>>4)*4+r, col=lane&15
            float sg = sigf(acc[mi][ni][r] + b4v[ni]);
            float hn = fmaf(qc[mi][r], kcj[ni], sg*hreg[mi][ni][r]);
            hreg[mi][ni][r] = hn;
            s.hfs[n*HFS + j]      = hn;
            s.hb[nxt][n*HBS + j]  = f2b(hn);
            part = fmaf(qn[mi][r], hn, part);
          }
        }
        part += __shfl_xor(part, 16);
        part += __shfl_xor(part, 32);
        if (g == 0) s.htp[mg*128 + j] = part;
      }
    }
    bar_lds();                             // B4: hfs/hb[nxt]/htp ready

    // ---- D: ht reduce + cat3 shift + HTg + coalesced H copy + qe prefetch write
    if (tid < 128){
      float ht = s.htp[tid] + s.htp[128 + tid];
      unsigned short curl = s.cat3[128 + tid];
      s.cat3[tid]       = curl;
      s.cat3[128 + tid] = f2b(qav);
      s.cat3[256 + tid] = f2b(ht);
      HTg[((size_t)b*T_ + t + 1)*128 + tid] = f2b(ht);
    } else if (tid >= 256 && tid < 320){
      if (t+2 < T_) s.qe[(t+2)%3][tid-256] = qmxv;
    }
    if (t < T_-2){
      float* Ho = H + ((size_t)(t+1)*B_ + b)*8192;
#pragma unroll
      for (int k = 0; k < 4; ++k){
        int f = tid + k*512;                 // float4 index in [0,2048)
        int n = f >> 5, d = (f & 31)*4;
        f32x4 v = *(const f32x4*)&s.hfs[n*HFS + d];
        *(f32x4*)&Ho[n*128 + d] = v;         // raw h; sig_k applies sigmoid later
      }
    }
    bar_lds();                             // B5: cat3/qe ready for next step
  }
}

// ---------------- sig_k: in-place sigmoid of H[1..126] ---------------------------
__global__ __launch_bounds__(256) void sig_k(float* __restrict__ H)
{
  const size_t n4 = (size_t)126*32*2048;   // float4 count
  f32x4* p = (f32x4*)(H + (size_t)32*8192);
  for (size_t i = (size_t)blockIdx.x*256 + threadIdx.x; i < n4; i += (size_t)gridDim.x*256){
    f32x4 v = p[i];
    v[0] = sigf(v[0]); v[1] = sigf(v[1]); v[2] = sigf(v[2]); v[3] = sigf(v[3]);
    p[i] = v;
  }
}

// ---------------- ypost: deferred y GEMV over all (b, tau>=1) --------------------
__global__ __launch_bounds__(256) void ypost_k(
    const float* __restrict__ oqe, const unsigned short* __restrict__ HT,
    const float* __restrict__ W5, const float* __restrict__ b5,
    float* __restrict__ pred)
{
  __shared__ float X[32][256];
  __shared__ float w5c[128][33];
  const int tau = blockIdx.x + 1;
  const int tid = threadIdx.x;

  for (int i = tid; i < 32*128; i += 256){
    int bb = i >> 7, k = i & 127;
    X[bb][k] = oqe[((size_t)bb*T_ + tau)*128 + k];
    union { unsigned int u; float f; } cv;
    cv.u = ((unsigned int)HT[((size_t)bb*T_ + tau)*128 + k]) << 16;
    X[bb][128 + k] = cv.f;
  }
  const int j = tid & 127, rh = tid >> 7;
  float acc[16];
  float base = b5[j];
#pragma unroll
  for (int r = 0; r < 16; ++r) acc[r] = base;
  for (int c = 0; c < 8; ++c){
    __syncthreads();
    for (int i = tid; i < 128*32; i += 256){
      int jj = i >> 5, kk = i & 31;
      w5c[jj][kk] = W5[(size_t)jj*256 + c*32 + kk];
    }
    __syncthreads();
#pragma unroll 8
    for (int k = 0; k < 32; ++k){
      float wv = w5c[j][k];
#pragma unroll
      for (int r = 0; r < 16; ++r) acc[r] = fmaf(X[rh*16 + r][c*32 + k], wv, acc[r]);
    }
  }
  __syncthreads();
#pragma unroll
  for (int r = 0; r < 16; ++r) X[rh*16 + r][j] = sigf(acc[r]);
  __syncthreads();
  if (tid < 32){
    float ssum = 0.f;
    for (int k = 0; k < 128; ++k) ssum += X[tid][k];
    pred[tid*T_ + tau] = ssum * (1.f/128.f);
  }
}

extern "C" void kernel_launch(void* const* d_in, const int* in_sizes, int n_in,
                              void* d_out, int out_size, void* d_ws, size_t ws_size,
                              hipStream_t stream)
{
  const int*   qd  = (const int*)  d_in[0];
  const float* ad  = (const float*)d_in[1];
  const float* qmx = (const float*)d_in[2];
  const float* qew = (const float*)d_in[3];
  const float* W1  = (const float*)d_in[4];
  const float* b1  = (const float*)d_in[5];
  const float* W2  = (const float*)d_in[6];
  const float* b2  = (const float*)d_in[7];
  const float* W3  = (const float*)d_in[8];
  const float* b3  = (const float*)d_in[9];
  const float* W4  = (const float*)d_in[10];
  const float* b4  = (const float*)d_in[11];
  const float* W5  = (const float*)d_in[12];
  const float* b5  = (const float*)d_in[13];
  const float* h0  = (const float*)d_in[14];

  float* H    = (float*)d_out;                         // [127][32][64][128]
  float* pred = H    + (size_t)127*32*64*128;          // [32][128]
  float* oqe  = pred + (size_t)32*128;                 // [32][128][128]
  float* oqa  = oqe  + (size_t)32*128*128;             // [32][128][128]

  unsigned short* W2b = (unsigned short*)d_ws;         // [128][384] bf16
  unsigned short* W3b = W2b + 128*384;
  unsigned short* W4b = W3b + 128*384;                 // [128][256] bf16
  float*          S   = (float*)(W4b + 128*256);       // [128]
  unsigned short* HTg = (unsigned short*)(S + 128);    // [32][128][128] bf16 h_tilde

  stage_k<<<192, 256, 0, stream>>>(W2, W3, W4, W1, W2b, W3b, W4b, S);
  prep_k <<<256, 256, 0, stream>>>(qd, ad, qew, W1, b1, S, oqe, oqa, pred);
  recur_k<<<32,  512, 0, stream>>>(qd, qmx, h0, b2, b3, b4,
                                   W2b, W3b, W4b, oqa, H, HTg);
  sig_k  <<<2048, 256, 0, stream>>>(H);
  ypost_k<<<127, 256, 0, stream>>>(oqe, HTg, W5, b5, pred);
}